// Round 1
// baseline (3116.385 us; speedup 1.0000x reference)
//
#include <hip/hip_runtime.h>
#include <stdint.h>
#include <string.h>

#define PXI 4800
#define BNI 24

typedef short bf16x8 __attribute__((ext_vector_type(8)));
typedef float f32x4 __attribute__((ext_vector_type(4)));

__device__ __forceinline__ uint16_t f2b(float f) {
  uint32_t u = __float_as_uint(f);
  u += 0x7fffu + ((u >> 16) & 1u);
  return (uint16_t)(u >> 16);
}
__device__ __forceinline__ float b2f(uint16_t b) {
  return __uint_as_float(((uint32_t)b) << 16);
}
__device__ __forceinline__ float sigm(float x) {
  return 1.0f / (1.0f + __expf(-x));
}

struct SrcDesc {
  const void* p;
  int nstride;    // elements per image
  int coff;       // starting channel of this 32-ch kstep within source
  int pixstride;  // NHWC channel count (bf16 path)
  int creal;      // valid channel bound (f32 path)
  int is_f32;     // 1 = NCHW f32 source, 0 = NHWC bf16 source
};

struct ConvParams {
  SrcDesc srcs[14];
  int KS, ntaps, pad, cog_total, mode;
  const uint16_t* wpk;
  const float* bias0;
  const float* bias1;
  uint16_t* out0; int ostride0, ochoff0;
  uint16_t* out1; int ostride1, ochoff1;
  const uint16_t* zbuf;   // mode 2
  const float* netf32;    // mode 1/2: h (f32 NCHW)
  float* houtf32;         // mode 2: net_out region of d_out
};

// Implicit-GEMM conv: one block = one output row (80 px) x (64*G) couts.
// A (weights) pre-packed in MFMA fragment order; B staged [80 px][32 ch] bf16
// with XOR swizzle on address bits 4..6.
template<int G>
__global__ __launch_bounds__(256) void conv_mfma(ConvParams P) {
  constexpr int ABYTES = 4 * G * 1024;
  __shared__ __align__(16) uint8_t smem[ABYTES + 5120];
  const int tid = threadIdx.x;
  const int wave = tid >> 6, lane = tid & 63;
  const int blk = blockIdx.x;
  const int n = blk / 60, y = blk % 60;
  const int cogBase = blockIdx.y * 4 * G;

  f32x4 acc[G][5];
  for (int g = 0; g < G; ++g)
    for (int t = 0; t < 5; ++t)
      acc[g][t] = f32x4{0.f, 0.f, 0.f, 0.f};

  const int abase = lane * 16;
  const int bbase = (((lane & 15) * 64 + ((lane >> 4) * 16)) ^ ((lane & 7) << 4));

  for (int tap = 0; tap < P.ntaps; ++tap) {
    const int dy = tap / 3, dxm = tap - dy * 3;
    const int ysrc = y + dy - P.pad;
    const bool yok = (unsigned)ysrc < 60u;
    const int rowoff = ysrc * 80;
    for (int ks = 0; ks < P.KS; ++ks) {
      __syncthreads();
      // ---- stage A: fragment-order weights, linear 16B copies
      for (int c = tid; c < 4 * G * 64; c += 256) {
        int cog = c >> 6, ln = c & 63;
        size_t boff = ((size_t)(tap * P.cog_total + cogBase + cog) * P.KS + ks) * 512;
        *(uint4*)(smem + cog * 1024 + ln * 16) = ((const uint4*)(P.wpk + boff))[ln];
      }
      // ---- stage B: shifted 80-px window x 32 channels
      const SrcDesc d = P.srcs[ks];
      if (!d.is_f32) {
        const uint16_t* bp = (const uint16_t*)d.p + (size_t)n * d.nstride + d.coff;
        for (int c = tid; c < 320; c += 256) {
          int x = c >> 2, kq = c & 3;
          int xs = x + dxm - P.pad;
          uint4 v; v.x = 0; v.y = 0; v.z = 0; v.w = 0;
          if (yok && (unsigned)xs < 80u)
            v = *(const uint4*)(bp + (size_t)(rowoff + xs) * d.pixstride + kq * 8);
          *(uint4*)(smem + ABYTES + ((x * 64 + kq * 16) ^ ((x & 7) << 4))) = v;
        }
      } else {
        const int ci = tid >> 3, xg = tid & 7;
        const bool cok = (d.coff + ci) < d.creal;
        const float* fp = (const float*)d.p + (size_t)n * d.nstride +
                          (size_t)(d.coff + ci) * PXI + rowoff;
#pragma unroll
        for (int j = 0; j < 10; ++j) {
          int x = xg + j * 8;
          int xs = x + dxm - P.pad;
          float v = 0.f;
          if (yok && cok && (unsigned)xs < 80u) v = fp[xs];
          *(uint16_t*)(smem + ABYTES + ((x * 64 + ci * 2) ^ ((x & 7) << 4))) = f2b(v);
        }
      }
      __syncthreads();
      // ---- MFMA
      bf16x8 a[G];
#pragma unroll
      for (int g = 0; g < G; ++g)
        a[g] = *(const bf16x8*)(smem + (wave * G + g) * 1024 + abase);
#pragma unroll
      for (int t = 0; t < 5; ++t) {
        bf16x8 b = *(const bf16x8*)(smem + ABYTES + t * 1024 + bbase);
#pragma unroll
        for (int g = 0; g < G; ++g)
          acc[g][t] = __builtin_amdgcn_mfma_f32_16x16x32_bf16(a[g], b, acc[g][t], 0, 0, 0);
      }
    }
  }

  // ---- epilogue
  const int pxl = lane & 15, rq = lane >> 4;
  for (int g = 0; g < G; ++g) {
    const int co0 = (cogBase + wave * G + g) * 16 + rq * 4;
    for (int t = 0; t < 5; ++t) {
      const int px = y * 80 + t * 16 + pxl;
      const size_t gpix = (size_t)n * PXI + px;
      float v[4];
#pragma unroll
      for (int rr = 0; rr < 4; ++rr) {
        int co = co0 + rr;
        float bia = (P.bias1 && co >= 128) ? P.bias1[co - 128] : P.bias0[co];
        v[rr] = acc[g][t][rr] + bia;
      }
      if (P.mode == 0) {           // relu -> bf16 NHWC (split at co>=128 if out1)
        uint16_t* op; int cb;
        if (P.out1 && co0 >= 128) { op = P.out1 + gpix * (size_t)P.ostride1 + P.ochoff1; cb = co0 - 128; }
        else                      { op = P.out0 + gpix * (size_t)P.ostride0 + P.ochoff0; cb = co0; }
        uint64_t w = 0;
#pragma unroll
        for (int rr = 0; rr < 4; ++rr)
          w |= (uint64_t)f2b(fmaxf(v[rr], 0.f)) << (16 * rr);
        *(uint64_t*)(op + cb) = w;
      } else if (P.mode == 1) {    // z (sigmoid) / r (sigmoid * h)
        if (co0 < 128) {
          uint64_t w = 0;
#pragma unroll
          for (int rr = 0; rr < 4; ++rr)
            w |= (uint64_t)f2b(sigm(v[rr])) << (16 * rr);
          *(uint64_t*)(P.out0 + gpix * 128 + co0) = w;
        } else {
          uint64_t w = 0;
#pragma unroll
          for (int rr = 0; rr < 4; ++rr) {
            float rg = sigm(v[rr]);
            float h = P.netf32[((size_t)n * 128 + (co0 - 128 + rr)) * PXI + px];
            w |= (uint64_t)f2b(rg * h) << (16 * rr);
          }
          *(uint64_t*)(P.out1 + gpix * 128 + (co0 - 128)) = w;
        }
      } else {                     // mode 2: q=tanh, GRU update, dual write
        uint64_t zw = *(const uint64_t*)(P.zbuf + gpix * 128 + co0);
        uint64_t w = 0;
#pragma unroll
        for (int rr = 0; rr < 4; ++rr) {
          float qv = tanhf(v[rr]);
          float z = b2f((uint16_t)(zw >> (16 * rr)));
          size_t hidx = ((size_t)n * 128 + co0 + rr) * PXI + px;
          float h = P.netf32[hidx];
          float hn = (1.f - z) * h + z * qv;
          P.houtf32[hidx] = hn;
          w |= (uint64_t)f2b(hn) << (16 * rr);
        }
        *(uint64_t*)(P.out0 + gpix * 128 + co0) = w;
      }
    }
  }
}

// Pack f32 OIHW weights -> bf16 MFMA-fragment-order:
// wpk[((tap*cogTotal + cog)*KS + ks)*512 + lane*8 + e],
// lane = (co&15) | (((ci>>3)&3)<<4), e = ci&7, ks = ci>>5. Cin zero-padded to CPAD.
__global__ __launch_bounds__(256) void pack_w(const float* w, uint16_t* wpk,
    int Cout, int Cin, int taps, int CPAD, int cobase, int cogTotal) {
  int idx = blockIdx.x * 256 + threadIdx.x;
  int total = Cout * CPAD * taps;
  if (idx >= total) return;
  int ci = idx % CPAD;
  int rest = idx / CPAD;
  int co = rest % Cout;
  int tap = rest / Cout;
  float v = (ci < Cin) ? w[((size_t)co * Cin + ci) * taps + tap] : 0.f;
  int cog = (cobase + co) >> 4;
  int ks = ci >> 5;
  int lane = ((cobase + co) & 15) | (((ci >> 3) & 3) << 4);
  int KS = CPAD >> 5;
  size_t off = ((size_t)(tap * cogTotal + cog) * KS + ks) * 512 + lane * 8 + (ci & 7);
  wpk[off] = f2b(v);
}

// flow encoder conv1: 7x7, Cin=3, pad=3, relu -> bf16 NHWC [n][px][128]
__global__ __launch_bounds__(256) void fe1_kernel(const float* flow, const float* w,
                                                  const float* bias, uint16_t* F1) {
  __shared__ float pat[3 * 22 * 24];
  __shared__ float wl[16 * 147];
  const int n = blockIdx.z, y0 = blockIdx.y * 16, x0 = blockIdx.x * 16;
  const int tid = threadIdx.x;
  for (int c = tid; c < 3 * 22 * 22; c += 256) {
    int ci = c / 484; int rem = c - ci * 484; int py = rem / 22; int px = rem - py * 22;
    int gy = y0 + py - 3, gx = x0 + px - 3;
    float v = 0.f;
    if ((unsigned)gy < 60u && (unsigned)gx < 80u)
      v = flow[((size_t)(n * 3 + ci) * 60 + gy) * 80 + gx];
    pat[(ci * 22 + py) * 24 + px] = v;
  }
  const int ty = tid >> 4, tx = tid & 15;
  const int yy = y0 + ty, xx = x0 + tx;
  const bool ok = (yy < 60);
  for (int cc = 0; cc < 8; ++cc) {
    __syncthreads();
    for (int c = tid; c < 16 * 147; c += 256) {
      int col = c / 147, k = c - col * 147;
      wl[c] = w[(size_t)(cc * 16 + col) * 147 + k];
    }
    __syncthreads();
    if (ok) {
      size_t obase = ((size_t)n * PXI + yy * 80 + xx) * 128 + cc * 16;
      for (int col = 0; col < 16; ++col) {
        float a = bias[cc * 16 + col];
        const float* wp = &wl[col * 147];
#pragma unroll
        for (int ci = 0; ci < 3; ++ci) {
          const float* pp = &pat[(ci * 22 + ty) * 24 + tx];
#pragma unroll
          for (int ky = 0; ky < 7; ++ky) {
#pragma unroll
            for (int kx = 0; kx < 7; ++kx)
              a += pp[ky * 24 + kx] * wp[ci * 49 + ky * 7 + kx];
          }
        }
        F1[obase + col] = f2b(fmaxf(a, 0.f));
      }
    }
  }
}

// heads conv2: 3x3, 128->3 each (delta raw, weight sigmoid), NHWC-transposed out
__global__ __launch_bounds__(256) void dw2_kernel(const uint16_t* D1, const uint16_t* W1,
    const float* wd, const float* wwt, const float* bd, const float* bw,
    float* out_delta, float* out_weight) {
  __shared__ float wl[2 * 3456];
  const int tid = threadIdx.x;
  for (int c = tid; c < 6912; c += 256)
    wl[c] = (c < 3456) ? wd[c] : wwt[c - 3456];
  __syncthreads();
  int gid = blockIdx.x * 256 + tid;
  if (gid >= BNI * PXI) return;
  int n = gid / PXI, px = gid - n * PXI;
  int y = px / 80, x = px - y * 80;
  float accd[3] = {bd[0], bd[1], bd[2]};
  float accw[3] = {bw[0], bw[1], bw[2]};
  for (int tap = 0; tap < 9; ++tap) {
    int dy = tap / 3, dxm = tap - dy * 3;
    int ys = y + dy - 1, xs = x + dxm - 1;
    if ((unsigned)ys >= 60u || (unsigned)xs >= 80u) continue;
    const uint16_t* dp = D1 + ((size_t)n * PXI + ys * 80 + xs) * 128;
    const uint16_t* wp = W1 + ((size_t)n * PXI + ys * 80 + xs) * 128;
    for (int ci = 0; ci < 128; ++ci) {
      float dv = b2f(dp[ci]);
      float wv = b2f(wp[ci]);
#pragma unroll
      for (int j = 0; j < 3; ++j) {
        accd[j] += dv * wl[(j * 128 + ci) * 9 + tap];
        accw[j] += wv * wl[3456 + (j * 128 + ci) * 9 + tap];
      }
    }
  }
  size_t ob = ((size_t)n * PXI + px) * 3;
#pragma unroll
  for (int j = 0; j < 3; ++j) {
    out_delta[ob + j] = accd[j];
    out_weight[ob + j] = sigm(accw[j]);
  }
}

extern "C" void kernel_launch(void* const* d_in, const int* in_sizes, int n_in,
                              void* d_out, int out_size, void* d_ws, size_t ws_size,
                              hipStream_t stream) {
  (void)in_sizes; (void)n_in; (void)out_size; (void)ws_size;
  const float* net  = (const float*)d_in[0];
  const float* inp  = (const float*)d_in[1];
  const float* corr = (const float*)d_in[2];
  const float* flow = (const float*)d_in[3];
  const float* w_ce1 = (const float*)d_in[4];   const float* b_ce1 = (const float*)d_in[5];
  const float* w_ce2 = (const float*)d_in[6];   const float* b_ce2 = (const float*)d_in[7];
  const float* w_fe1 = (const float*)d_in[8];   const float* b_fe1 = (const float*)d_in[9];
  const float* w_fe2 = (const float*)d_in[10];  const float* b_fe2 = (const float*)d_in[11];
  const float* w_z  = (const float*)d_in[12];   const float* b_z  = (const float*)d_in[13];
  const float* w_r  = (const float*)d_in[14];   const float* b_r  = (const float*)d_in[15];
  const float* w_q  = (const float*)d_in[16];   const float* b_q  = (const float*)d_in[17];
  const float* w_d1 = (const float*)d_in[18];   const float* b_d1 = (const float*)d_in[19];
  const float* w_d2 = (const float*)d_in[20];   const float* b_d2 = (const float*)d_in[21];
  const float* w_w1 = (const float*)d_in[22];   const float* b_w1 = (const float*)d_in[23];
  const float* w_w2 = (const float*)d_in[24];   const float* b_w2 = (const float*)d_in[25];

  uint8_t* ws = (uint8_t*)d_ws;
  size_t off = 0;
  auto alloc = [&](size_t b) { size_t o = off; off += (b + 255) & ~(size_t)255; return o; };
  uint16_t* wpk_ce1 = (uint16_t*)(ws + alloc(57344));
  uint16_t* wpk_ce2 = (uint16_t*)(ws + alloc(294912));
  uint16_t* wpk_fe2 = (uint16_t*)(ws + alloc(147456));
  uint16_t* wpk_zr  = (uint16_t*)(ws + alloc(2064384));
  uint16_t* wpk_q   = (uint16_t*)(ws + alloc(1032192));
  uint16_t* wpk_dw  = (uint16_t*)(ws + alloc(589824));
  uint16_t* X192 = (uint16_t*)(ws + alloc((size_t)BNI * PXI * 192 * 2));  // [inp? no: c(0..127), fl(128..191)]
  uint16_t* R1   = (uint16_t*)(ws + alloc((size_t)BNI * PXI * 128 * 2));  // C1 -> Z -> D1
  uint16_t* R2   = (uint16_t*)(ws + alloc((size_t)BNI * PXI * 128 * 2));  // F1 -> RH -> W1
  uint16_t* HN   = (uint16_t*)(ws + alloc((size_t)BNI * PXI * 128 * 2));  // h_new bf16

  auto packs = [&](const float* w, uint16_t* dst, int Cout, int Cin, int taps,
                   int CPAD, int cobase, int cogT) {
    int total = Cout * CPAD * taps;
    pack_w<<<(total + 255) / 256, 256, 0, stream>>>(w, dst, Cout, Cin, taps, CPAD, cobase, cogT);
  };
  packs(w_ce1, wpk_ce1, 128, 197, 1, 224, 0, 8);
  packs(w_ce2, wpk_ce2, 128, 128, 9, 128, 0, 8);
  packs(w_fe2, wpk_fe2, 64, 128, 9, 128, 0, 4);
  packs(w_z,  wpk_zr, 128, 448, 9, 448, 0, 16);
  packs(w_r,  wpk_zr, 128, 448, 9, 448, 128, 16);
  packs(w_q,  wpk_q,  128, 448, 9, 448, 0, 8);
  packs(w_d1, wpk_dw, 128, 128, 9, 128, 0, 16);
  packs(w_w1, wpk_dw, 128, 128, 9, 128, 128, 16);

  fe1_kernel<<<dim3(5, 4, 24), 256, 0, stream>>>(flow, w_fe1, b_fe1, R2);

  ConvParams p;
  // ---- ce1: 1x1, corr(197 f32) -> C1(R1), relu
  memset(&p, 0, sizeof(p));
  for (int ks = 0; ks < 7; ++ks) p.srcs[ks] = SrcDesc{corr, 197 * PXI, ks * 32, 0, 197, 1};
  p.KS = 7; p.ntaps = 1; p.pad = 0; p.cog_total = 8; p.mode = 0;
  p.wpk = wpk_ce1; p.bias0 = b_ce1;
  p.out0 = R1; p.ostride0 = 128; p.ochoff0 = 0;
  conv_mfma<2><<<dim3(1440, 1), 256, 0, stream>>>(p);
  // ---- ce2: 3x3, C1 -> X192[0:128), relu
  memset(&p, 0, sizeof(p));
  for (int ks = 0; ks < 4; ++ks) p.srcs[ks] = SrcDesc{R1, PXI * 128, ks * 32, 128, 0, 0};
  p.KS = 4; p.ntaps = 9; p.pad = 1; p.cog_total = 8; p.mode = 0;
  p.wpk = wpk_ce2; p.bias0 = b_ce2;
  p.out0 = X192; p.ostride0 = 192; p.ochoff0 = 0;
  conv_mfma<2><<<dim3(1440, 1), 256, 0, stream>>>(p);
  // ---- fe2: 3x3, F1(R2) -> X192[128:192), relu (Cout=64)
  memset(&p, 0, sizeof(p));
  for (int ks = 0; ks < 4; ++ks) p.srcs[ks] = SrcDesc{R2, PXI * 128, ks * 32, 128, 0, 0};
  p.KS = 4; p.ntaps = 9; p.pad = 1; p.cog_total = 4; p.mode = 0;
  p.wpk = wpk_fe2; p.bias0 = b_fe2;
  p.out0 = X192; p.ostride0 = 192; p.ochoff0 = 128;
  conv_mfma<1><<<dim3(1440, 1), 256, 0, stream>>>(p);
  // ---- z & r fused: 3x3, [net|inp|X192] -> Z(R1), RH(R2)
  memset(&p, 0, sizeof(p));
  for (int ks = 0; ks < 4; ++ks)  p.srcs[ks] = SrcDesc{net, 128 * PXI, ks * 32, 0, 128, 1};
  for (int ks = 4; ks < 8; ++ks)  p.srcs[ks] = SrcDesc{inp, 128 * PXI, (ks - 4) * 32, 0, 128, 1};
  for (int ks = 8; ks < 14; ++ks) p.srcs[ks] = SrcDesc{X192, PXI * 192, (ks - 8) * 32, 192, 0, 0};
  p.KS = 14; p.ntaps = 9; p.pad = 1; p.cog_total = 16; p.mode = 1;
  p.wpk = wpk_zr; p.bias0 = b_z; p.bias1 = b_r;
  p.out0 = R1; p.out1 = R2; p.netf32 = net;
  conv_mfma<2><<<dim3(1440, 2), 256, 0, stream>>>(p);
  // ---- q: 3x3, [RH|inp|X192] -> tanh, GRU update -> d_out(net) + HN
  memset(&p, 0, sizeof(p));
  for (int ks = 0; ks < 4; ++ks)  p.srcs[ks] = SrcDesc{R2, PXI * 128, ks * 32, 128, 0, 0};
  for (int ks = 4; ks < 8; ++ks)  p.srcs[ks] = SrcDesc{inp, 128 * PXI, (ks - 4) * 32, 0, 128, 1};
  for (int ks = 8; ks < 14; ++ks) p.srcs[ks] = SrcDesc{X192, PXI * 192, (ks - 8) * 32, 192, 0, 0};
  p.KS = 14; p.ntaps = 9; p.pad = 1; p.cog_total = 8; p.mode = 2;
  p.wpk = wpk_q; p.bias0 = b_q;
  p.out0 = HN; p.zbuf = R1; p.netf32 = net; p.houtf32 = (float*)d_out;
  conv_mfma<2><<<dim3(1440, 1), 256, 0, stream>>>(p);
  // ---- d1 & w1 fused: 3x3, HN -> D1(R1), W1(R2), relu
  memset(&p, 0, sizeof(p));
  for (int ks = 0; ks < 4; ++ks) p.srcs[ks] = SrcDesc{HN, PXI * 128, ks * 32, 128, 0, 0};
  p.KS = 4; p.ntaps = 9; p.pad = 1; p.cog_total = 16; p.mode = 0;
  p.wpk = wpk_dw; p.bias0 = b_d1; p.bias1 = b_w1;
  p.out0 = R1; p.ostride0 = 128; p.ochoff0 = 0;
  p.out1 = R2; p.ostride1 = 128; p.ochoff1 = 0;
  conv_mfma<2><<<dim3(1440, 2), 256, 0, stream>>>(p);
  // ---- heads final convs
  float* dout = (float*)d_out;
  dw2_kernel<<<450, 256, 0, stream>>>(R1, R2, w_d2, w_w2, b_d2, b_w2,
                                      dout + 14745600, dout + 15091200);
}

// Round 2
// 2198.016 us; speedup vs baseline: 1.4178x; 1.4178x over previous
//
#include <hip/hip_runtime.h>
#include <stdint.h>
#include <string.h>

#define PXI 4800
#define BNI 24

typedef short bf16x8 __attribute__((ext_vector_type(8)));
typedef float f32x4 __attribute__((ext_vector_type(4)));

__device__ __forceinline__ uint16_t f2b(float f) {
  uint32_t u = __float_as_uint(f);
  u += 0x7fffu + ((u >> 16) & 1u);
  return (uint16_t)(u >> 16);
}
__device__ __forceinline__ float b2f(uint16_t b) {
  return __uint_as_float(((uint32_t)b) << 16);
}
__device__ __forceinline__ float sigm(float x) {
  return 1.0f / (1.0f + __expf(-x));
}

struct SrcDesc {
  const void* p;
  int nstride;    // elements per image
  int coff;       // starting channel of this 32-ch kstep within source
  int pixstride;  // NHWC channel count (bf16 path)
  int creal;      // valid channel bound (f32 path)
  int is_f32;     // 1 = NCHW f32 source, 0 = NHWC bf16 source
};

struct ConvParams {
  SrcDesc srcs[14];
  int KS, ntaps, pad, cog_total, mode;
  const uint16_t* wpk;
  const float* bias0;
  const float* bias1;
  uint16_t* out0; int ostride0, ochoff0;
  uint16_t* out1; int ostride1, ochoff1;
  const uint16_t* zbuf;   // mode 2
  const float* netf32;    // mode 1/2: h (f32 NCHW)
  float* houtf32;         // mode 2: net_out region of d_out
};

// Implicit-GEMM conv v2: one block = one output row (80 px) x (64*G) couts.
// Halo B staging: 80+2*pad px x 32 ch staged ONCE per (dy,ks), read at DSPAN
// shifted offsets for the dx taps. A (weights) pre-packed in MFMA fragment
// order, staged for all DSPAN dx taps per (dy,ks). XOR swizzle on B addr
// bits 4..6 keeps ds_read_b128 conflicts ~2-way.
template<int G, int DSPAN>
__global__ __launch_bounds__(256) void conv_mfma(ConvParams P) {
  constexpr int ABYTES = DSPAN * 4 * G * 1024;
  __shared__ __align__(16) uint8_t smem[ABYTES + 5376];
  const int tid = threadIdx.x;
  const int wave = tid >> 6, lane = tid & 63;
  const int nbx = gridDim.x;
  const int bx = blockIdx.x;
  const int blk = (bx & 7) * (nbx >> 3) + (bx >> 3);  // XCD-contiguous rows
  const int n = blk / 60, y = blk % 60;
  const int cogBase = blockIdx.y * 4 * G;
  const int UP = 80 + 2 * P.pad;

  f32x4 acc[G][5];
#pragma unroll
  for (int g = 0; g < G; ++g)
#pragma unroll
    for (int t = 0; t < 5; ++t)
      acc[g][t] = f32x4{0.f, 0.f, 0.f, 0.f};

  const int pxl = lane & 15;
  const int abase = lane * 16;
  int bb[DSPAN];
#pragma unroll
  for (int dx = 0; dx < DSPAN; ++dx) {
    int u0 = pxl + dx;
    bb[dx] = ABYTES + ((u0 * 64 + ((lane >> 4) * 16)) ^ ((u0 & 7) << 4));
  }

  for (int dyi = 0; dyi < DSPAN; ++dyi) {
    const int ysrc = y + dyi - P.pad;
    const bool yok = (unsigned)ysrc < 60u;
    const int rowoff = ysrc * 80;
    for (int ks = 0; ks < P.KS; ++ks) {
      __syncthreads();
      // ---- stage A: DSPAN taps of fragment-order weights, linear 16B copies
      for (int c = tid; c < DSPAN * 256 * G; c += 256) {
        int dx = c / (256 * G);
        int idx = c >> 6;
        int cog = idx - dx * 4 * G;
        int ln = c & 63;
        int tap = (DSPAN == 3) ? (dyi * 3 + dx) : 0;
        size_t boff = ((size_t)(tap * P.cog_total + cogBase + cog) * P.KS + ks) * 512;
        *(uint4*)(smem + idx * 1024 + ln * 16) = ((const uint4*)(P.wpk + boff))[ln];
      }
      // ---- stage B: UP px (with halo) x 32 channels
      const SrcDesc d = P.srcs[ks];
      if (!d.is_f32) {
        const uint16_t* bp = (const uint16_t*)d.p + (size_t)n * d.nstride + d.coff;
        for (int c = tid; c < UP * 4; c += 256) {
          int u = c >> 2, kq = c & 3;
          int xs = u - P.pad;
          uint4 v; v.x = 0; v.y = 0; v.z = 0; v.w = 0;
          if (yok && (unsigned)xs < 80u)
            v = *(const uint4*)(bp + (size_t)(rowoff + xs) * d.pixstride + kq * 8);
          *(uint4*)(smem + ABYTES + ((u * 64 + kq * 16) ^ ((u & 7) << 4))) = v;
        }
      } else {
        // f32 NCHW path (ce1 only: 1x1 conv, pad==0)
        const int ci = tid >> 3, xg = tid & 7;
        const bool cok = (d.coff + ci) < d.creal;
        const float* fp = (const float*)d.p + (size_t)n * d.nstride +
                          (size_t)(d.coff + ci) * PXI + rowoff;
#pragma unroll
        for (int j = 0; j < 10; ++j) {
          int x = xg + j * 8;
          float v = 0.f;
          if (yok && cok) v = fp[x];
          *(uint16_t*)(smem + ABYTES + ((x * 64 + ci * 2) ^ ((x & 7) << 4))) = f2b(v);
        }
      }
      __syncthreads();
      // ---- MFMA: DSPAN dx taps x 5 px tiles x G cogs
#pragma unroll
      for (int dx = 0; dx < DSPAN; ++dx) {
        bf16x8 a[G];
#pragma unroll
        for (int g = 0; g < G; ++g)
          a[g] = *(const bf16x8*)(smem + (dx * 4 * G + wave * G + g) * 1024 + abase);
#pragma unroll
        for (int t = 0; t < 5; ++t) {
          bf16x8 b = *(const bf16x8*)(smem + bb[dx] + t * 1024);
#pragma unroll
          for (int g = 0; g < G; ++g)
            acc[g][t] = __builtin_amdgcn_mfma_f32_16x16x32_bf16(a[g], b, acc[g][t], 0, 0, 0);
        }
      }
    }
  }

  // ---- epilogue
  const int rq = lane >> 4;
  for (int g = 0; g < G; ++g) {
    const int co0 = (cogBase + wave * G + g) * 16 + rq * 4;
    for (int t = 0; t < 5; ++t) {
      const int px = y * 80 + t * 16 + pxl;
      const size_t gpix = (size_t)n * PXI + px;
      float v[4];
#pragma unroll
      for (int rr = 0; rr < 4; ++rr) {
        int co = co0 + rr;
        float bia = (P.bias1 && co >= 128) ? P.bias1[co - 128] : P.bias0[co];
        v[rr] = acc[g][t][rr] + bia;
      }
      if (P.mode == 0) {           // relu -> bf16 NHWC (split at co>=128 if out1)
        uint16_t* op; int cb;
        if (P.out1 && co0 >= 128) { op = P.out1 + gpix * (size_t)P.ostride1 + P.ochoff1; cb = co0 - 128; }
        else                      { op = P.out0 + gpix * (size_t)P.ostride0 + P.ochoff0; cb = co0; }
        uint64_t w = 0;
#pragma unroll
        for (int rr = 0; rr < 4; ++rr)
          w |= (uint64_t)f2b(fmaxf(v[rr], 0.f)) << (16 * rr);
        *(uint64_t*)(op + cb) = w;
      } else if (P.mode == 1) {    // z (sigmoid) / r (sigmoid * h)
        if (co0 < 128) {
          uint64_t w = 0;
#pragma unroll
          for (int rr = 0; rr < 4; ++rr)
            w |= (uint64_t)f2b(sigm(v[rr])) << (16 * rr);
          *(uint64_t*)(P.out0 + gpix * 128 + co0) = w;
        } else {
          uint64_t w = 0;
#pragma unroll
          for (int rr = 0; rr < 4; ++rr) {
            float rg = sigm(v[rr]);
            float h = P.netf32[((size_t)n * 128 + (co0 - 128 + rr)) * PXI + px];
            w |= (uint64_t)f2b(rg * h) << (16 * rr);
          }
          *(uint64_t*)(P.out1 + gpix * 128 + (co0 - 128)) = w;
        }
      } else {                     // mode 2: q=tanh, GRU update, dual write
        uint64_t zw = *(const uint64_t*)(P.zbuf + gpix * 128 + co0);
        uint64_t w = 0;
#pragma unroll
        for (int rr = 0; rr < 4; ++rr) {
          float qv = tanhf(v[rr]);
          float z = b2f((uint16_t)(zw >> (16 * rr)));
          size_t hidx = ((size_t)n * 128 + co0 + rr) * PXI + px;
          float h = P.netf32[hidx];
          float hn = (1.f - z) * h + z * qv;
          P.houtf32[hidx] = hn;
          w |= (uint64_t)f2b(hn) << (16 * rr);
        }
        *(uint64_t*)(P.out0 + gpix * 128 + co0) = w;
      }
    }
  }
}

// f32 NCHW -> bf16 NHWC transpose (coalesced reads across lanes per channel)
__global__ __launch_bounds__(256) void nchw2nhwc(const float* src, uint16_t* dst,
                                                 int C, int pixstride, int choff) {
  const int n = blockIdx.y;
  const int px = blockIdx.x * 256 + threadIdx.x;
  if (px >= PXI) return;
  const float* sp = src + (size_t)n * C * PXI + px;
  uint16_t* dp = dst + ((size_t)n * PXI + px) * pixstride + choff;
  for (int c = 0; c < C; c += 8) {
    uint32_t pk[4];
#pragma unroll
    for (int j = 0; j < 4; ++j) {
      uint32_t lo = f2b(sp[(size_t)(c + 2 * j) * PXI]);
      uint32_t hi = f2b(sp[(size_t)(c + 2 * j + 1) * PXI]);
      pk[j] = lo | (hi << 16);
    }
    uint4 v; v.x = pk[0]; v.y = pk[1]; v.z = pk[2]; v.w = pk[3];
    *(uint4*)(dp + c) = v;
  }
}

// Pack f32 OIHW weights -> bf16 MFMA-fragment-order:
// wpk[((tap*cogTotal + cog)*KS + ks)*512 + lane*8 + e],
// lane = (co&15) | (((ci>>3)&3)<<4), e = ci&7, ks = ci>>5. Cin zero-padded to CPAD.
__global__ __launch_bounds__(256) void pack_w(const float* w, uint16_t* wpk,
    int Cout, int Cin, int taps, int CPAD, int cobase, int cogTotal) {
  int idx = blockIdx.x * 256 + threadIdx.x;
  int total = Cout * CPAD * taps;
  if (idx >= total) return;
  int ci = idx % CPAD;
  int rest = idx / CPAD;
  int co = rest % Cout;
  int tap = rest / Cout;
  float v = (ci < Cin) ? w[((size_t)co * Cin + ci) * taps + tap] : 0.f;
  int cog = (cobase + co) >> 4;
  int ks = ci >> 5;
  int lane = ((cobase + co) & 15) | (((ci >> 3) & 3) << 4);
  int KS = CPAD >> 5;
  size_t off = ((size_t)(tap * cogTotal + cog) * KS + ks) * 512 + lane * 8 + (ci & 7);
  wpk[off] = f2b(v);
}

// flow encoder conv1: 7x7, Cin=3, pad=3, relu -> bf16 NHWC [n][px][128]
__global__ __launch_bounds__(256) void fe1_kernel(const float* flow, const float* w,
                                                  const float* bias, uint16_t* F1) {
  __shared__ float pat[3 * 22 * 24];
  __shared__ float wl[16 * 147];
  const int n = blockIdx.z, y0 = blockIdx.y * 16, x0 = blockIdx.x * 16;
  const int tid = threadIdx.x;
  for (int c = tid; c < 3 * 22 * 22; c += 256) {
    int ci = c / 484; int rem = c - ci * 484; int py = rem / 22; int px = rem - py * 22;
    int gy = y0 + py - 3, gx = x0 + px - 3;
    float v = 0.f;
    if ((unsigned)gy < 60u && (unsigned)gx < 80u)
      v = flow[((size_t)(n * 3 + ci) * 60 + gy) * 80 + gx];
    pat[(ci * 22 + py) * 24 + px] = v;
  }
  const int ty = tid >> 4, tx = tid & 15;
  const int yy = y0 + ty, xx = x0 + tx;
  const bool ok = (yy < 60);
  for (int cc = 0; cc < 8; ++cc) {
    __syncthreads();
    for (int c = tid; c < 16 * 147; c += 256) {
      int col = c / 147, k = c - col * 147;
      wl[c] = w[(size_t)(cc * 16 + col) * 147 + k];
    }
    __syncthreads();
    if (ok) {
      size_t obase = ((size_t)n * PXI + yy * 80 + xx) * 128 + cc * 16;
      for (int col = 0; col < 16; ++col) {
        float a = bias[cc * 16 + col];
        const float* wp = &wl[col * 147];
#pragma unroll
        for (int ci = 0; ci < 3; ++ci) {
          const float* pp = &pat[(ci * 22 + ty) * 24 + tx];
#pragma unroll
          for (int ky = 0; ky < 7; ++ky) {
#pragma unroll
            for (int kx = 0; kx < 7; ++kx)
              a += pp[ky * 24 + kx] * wp[ci * 49 + ky * 7 + kx];
          }
        }
        F1[obase + col] = f2b(fmaxf(a, 0.f));
      }
    }
  }
}

// heads conv2: 3x3, 128->3 each (delta raw, weight sigmoid), NHWC-transposed out
__global__ __launch_bounds__(256) void dw2_kernel(const uint16_t* D1, const uint16_t* W1,
    const float* wd, const float* wwt, const float* bd, const float* bw,
    float* out_delta, float* out_weight) {
  __shared__ float wl[2 * 3456];
  const int tid = threadIdx.x;
  for (int c = tid; c < 6912; c += 256)
    wl[c] = (c < 3456) ? wd[c] : wwt[c - 3456];
  __syncthreads();
  int gid = blockIdx.x * 256 + tid;
  if (gid >= BNI * PXI) return;
  int n = gid / PXI, px = gid - n * PXI;
  int y = px / 80, x = px - y * 80;
  float accd[3] = {bd[0], bd[1], bd[2]};
  float accw[3] = {bw[0], bw[1], bw[2]};
  for (int tap = 0; tap < 9; ++tap) {
    int dy = tap / 3, dxm = tap - dy * 3;
    int ys = y + dy - 1, xs = x + dxm - 1;
    if ((unsigned)ys >= 60u || (unsigned)xs >= 80u) continue;
    const uint16_t* dp = D1 + ((size_t)n * PXI + ys * 80 + xs) * 128;
    const uint16_t* wp = W1 + ((size_t)n * PXI + ys * 80 + xs) * 128;
    for (int ci = 0; ci < 128; ++ci) {
      float dv = b2f(dp[ci]);
      float wv = b2f(wp[ci]);
#pragma unroll
      for (int j = 0; j < 3; ++j) {
        accd[j] += dv * wl[(j * 128 + ci) * 9 + tap];
        accw[j] += wv * wl[3456 + (j * 128 + ci) * 9 + tap];
      }
    }
  }
  size_t ob = ((size_t)n * PXI + px) * 3;
#pragma unroll
  for (int j = 0; j < 3; ++j) {
    out_delta[ob + j] = accd[j];
    out_weight[ob + j] = sigm(accw[j]);
  }
}

extern "C" void kernel_launch(void* const* d_in, const int* in_sizes, int n_in,
                              void* d_out, int out_size, void* d_ws, size_t ws_size,
                              hipStream_t stream) {
  (void)in_sizes; (void)n_in; (void)out_size; (void)ws_size;
  const float* net  = (const float*)d_in[0];
  const float* inp  = (const float*)d_in[1];
  const float* corr = (const float*)d_in[2];
  const float* flow = (const float*)d_in[3];
  const float* w_ce1 = (const float*)d_in[4];   const float* b_ce1 = (const float*)d_in[5];
  const float* w_ce2 = (const float*)d_in[6];   const float* b_ce2 = (const float*)d_in[7];
  const float* w_fe1 = (const float*)d_in[8];   const float* b_fe1 = (const float*)d_in[9];
  const float* w_fe2 = (const float*)d_in[10];  const float* b_fe2 = (const float*)d_in[11];
  const float* w_z  = (const float*)d_in[12];   const float* b_z  = (const float*)d_in[13];
  const float* w_r  = (const float*)d_in[14];   const float* b_r  = (const float*)d_in[15];
  const float* w_q  = (const float*)d_in[16];   const float* b_q  = (const float*)d_in[17];
  const float* w_d1 = (const float*)d_in[18];   const float* b_d1 = (const float*)d_in[19];
  const float* w_d2 = (const float*)d_in[20];   const float* b_d2 = (const float*)d_in[21];
  const float* w_w1 = (const float*)d_in[22];   const float* b_w1 = (const float*)d_in[23];
  const float* w_w2 = (const float*)d_in[24];   const float* b_w2 = (const float*)d_in[25];

  uint8_t* ws = (uint8_t*)d_ws;
  size_t off = 0;
  auto alloc = [&](size_t b) { size_t o = off; off += (b + 255) & ~(size_t)255; return o; };
  uint16_t* wpk_ce1 = (uint16_t*)(ws + alloc(57344));
  uint16_t* wpk_ce2 = (uint16_t*)(ws + alloc(294912));
  uint16_t* wpk_fe2 = (uint16_t*)(ws + alloc(147456));
  uint16_t* wpk_zr  = (uint16_t*)(ws + alloc(2064384));
  uint16_t* wpk_q   = (uint16_t*)(ws + alloc(1032192));
  uint16_t* wpk_dw  = (uint16_t*)(ws + alloc(589824));
  uint16_t* X448 = (uint16_t*)(ws + alloc((size_t)BNI * PXI * 448 * 2)); // [h|inp|c|fl]
  uint16_t* C1   = (uint16_t*)(ws + alloc((size_t)BNI * PXI * 128 * 2)); // ce1 out -> HN
  uint16_t* F1   = (uint16_t*)(ws + alloc((size_t)BNI * PXI * 128 * 2)); // fe1 out
  uint16_t* Zb   = (uint16_t*)(ws + alloc((size_t)BNI * PXI * 128 * 2)); // z -> D1
  uint16_t* RHb  = (uint16_t*)(ws + alloc((size_t)BNI * PXI * 128 * 2)); // r*h -> W1

  auto packs = [&](const float* w, uint16_t* dst, int Cout, int Cin, int taps,
                   int CPAD, int cobase, int cogT) {
    int total = Cout * CPAD * taps;
    pack_w<<<(total + 255) / 256, 256, 0, stream>>>(w, dst, Cout, Cin, taps, CPAD, cobase, cogT);
  };
  packs(w_ce1, wpk_ce1, 128, 197, 1, 224, 0, 8);
  packs(w_ce2, wpk_ce2, 128, 128, 9, 128, 0, 8);
  packs(w_fe2, wpk_fe2, 64, 128, 9, 128, 0, 4);
  packs(w_z,  wpk_zr, 128, 448, 9, 448, 0, 16);
  packs(w_r,  wpk_zr, 128, 448, 9, 448, 128, 16);
  packs(w_q,  wpk_q,  128, 448, 9, 448, 0, 8);
  packs(w_d1, wpk_dw, 128, 128, 9, 128, 0, 16);
  packs(w_w1, wpk_dw, 128, 128, 9, 128, 128, 16);

  nchw2nhwc<<<dim3(19, BNI), 256, 0, stream>>>(net, X448, 128, 448, 0);
  nchw2nhwc<<<dim3(19, BNI), 256, 0, stream>>>(inp, X448, 128, 448, 128);
  fe1_kernel<<<dim3(5, 4, 24), 256, 0, stream>>>(flow, w_fe1, b_fe1, F1);

  ConvParams p;
  // ---- ce1: 1x1, corr(197 f32) -> C1, relu
  memset(&p, 0, sizeof(p));
  for (int ks = 0; ks < 7; ++ks) p.srcs[ks] = SrcDesc{corr, 197 * PXI, ks * 32, 0, 197, 1};
  p.KS = 7; p.ntaps = 1; p.pad = 0; p.cog_total = 8; p.mode = 0;
  p.wpk = wpk_ce1; p.bias0 = b_ce1;
  p.out0 = C1; p.ostride0 = 128; p.ochoff0 = 0;
  conv_mfma<2, 1><<<dim3(1440, 1), 256, 0, stream>>>(p);
  // ---- ce2: 3x3, C1 -> X448[256:384), relu
  memset(&p, 0, sizeof(p));
  for (int ks = 0; ks < 4; ++ks) p.srcs[ks] = SrcDesc{C1, PXI * 128, ks * 32, 128, 0, 0};
  p.KS = 4; p.ntaps = 9; p.pad = 1; p.cog_total = 8; p.mode = 0;
  p.wpk = wpk_ce2; p.bias0 = b_ce2;
  p.out0 = X448; p.ostride0 = 448; p.ochoff0 = 256;
  conv_mfma<2, 3><<<dim3(1440, 1), 256, 0, stream>>>(p);
  // ---- fe2: 3x3, F1 -> X448[384:448), relu (Cout=64)
  memset(&p, 0, sizeof(p));
  for (int ks = 0; ks < 4; ++ks) p.srcs[ks] = SrcDesc{F1, PXI * 128, ks * 32, 128, 0, 0};
  p.KS = 4; p.ntaps = 9; p.pad = 1; p.cog_total = 4; p.mode = 0;
  p.wpk = wpk_fe2; p.bias0 = b_fe2;
  p.out0 = X448; p.ostride0 = 448; p.ochoff0 = 384;
  conv_mfma<1, 3><<<dim3(1440, 1), 256, 0, stream>>>(p);
  // ---- z & r fused: 3x3, X448 -> Z(Zb), RH(RHb)
  memset(&p, 0, sizeof(p));
  for (int ks = 0; ks < 14; ++ks) p.srcs[ks] = SrcDesc{X448, PXI * 448, ks * 32, 448, 0, 0};
  p.KS = 14; p.ntaps = 9; p.pad = 1; p.cog_total = 16; p.mode = 1;
  p.wpk = wpk_zr; p.bias0 = b_z; p.bias1 = b_r;
  p.out0 = Zb; p.out1 = RHb; p.netf32 = net;
  conv_mfma<2, 3><<<dim3(1440, 2), 256, 0, stream>>>(p);
  // ---- q: 3x3, [RH | X448[128:448)] -> tanh, GRU update -> d_out(net) + HN(C1)
  memset(&p, 0, sizeof(p));
  for (int ks = 0; ks < 4; ++ks)  p.srcs[ks] = SrcDesc{RHb, PXI * 128, ks * 32, 128, 0, 0};
  for (int ks = 4; ks < 14; ++ks) p.srcs[ks] = SrcDesc{X448, PXI * 448, 128 + (ks - 4) * 32, 448, 0, 0};
  p.KS = 14; p.ntaps = 9; p.pad = 1; p.cog_total = 8; p.mode = 2;
  p.wpk = wpk_q; p.bias0 = b_q;
  p.out0 = C1; p.zbuf = Zb; p.netf32 = net; p.houtf32 = (float*)d_out;
  conv_mfma<2, 3><<<dim3(1440, 1), 256, 0, stream>>>(p);
  // ---- d1 & w1 fused: 3x3, HN(C1) -> D1(Zb), W1(RHb), relu
  memset(&p, 0, sizeof(p));
  for (int ks = 0; ks < 4; ++ks) p.srcs[ks] = SrcDesc{C1, PXI * 128, ks * 32, 128, 0, 0};
  p.KS = 4; p.ntaps = 9; p.pad = 1; p.cog_total = 16; p.mode = 0;
  p.wpk = wpk_dw; p.bias0 = b_d1; p.bias1 = b_w1;
  p.out0 = Zb; p.ostride0 = 128; p.ochoff0 = 0;
  p.out1 = RHb; p.ostride1 = 128; p.ochoff1 = 0;
  conv_mfma<2, 3><<<dim3(1440, 2), 256, 0, stream>>>(p);
  // ---- heads final convs
  float* dout = (float*)d_out;
  dw2_kernel<<<450, 256, 0, stream>>>(Zb, RHb, w_d2, w_w2, b_d2, b_w2,
                                      dout + 14745600, dout + 15091200);
}